// Round 3
// baseline (259.098 us; speedup 1.0000x reference)
//
#include <hip/hip_runtime.h>
#include <math.h>
#include <stdint.h>

#define N512 512

typedef __attribute__((ext_vector_type(8))) short short8;
typedef __attribute__((ext_vector_type(4))) float floatx4;

#define VMCNT0 asm volatile("s_waitcnt vmcnt(0)" ::: "memory")

__device__ __forceinline__ short f2bf(float f) {
    uint32_t u = __float_as_uint(f);
    uint32_t r = u + 0x7fffu + ((u >> 16) & 1u);
    return (short)(r >> 16);
}

// cheap round-half-up (2 VALU): fine vs 0.109 threshold
__device__ __forceinline__ short f2bf_fast(float f) {
    return (short)((__float_as_uint(f) + 0x8000u) >> 16);
}

__device__ __forceinline__ void gload_lds16(const void* g, void* l) {
    __builtin_amdgcn_global_load_lds(
        (const __attribute__((address_space(1))) void*)g,
        (__attribute__((address_space(3))) void*)l,
        16, 0, 0);
}

// Per-wave tile decode with XCD-sibling grouping.
// B-panel id g = z*8 + ps (panel strip), sibling ms = A-strip 0..7.
// id = (g>>3)*64 + ms*8 + (g&7): the 8 siblings of a panel share id mod 8
// -> same XCD under round-robin -> panel served from one L2.
// Valid for any c (g-count = 8c is always divisible by 8).
__device__ __forceinline__ void decode_wave(int id, int& ms, int& ps, int& z) {
    const int g = (id >> 6) * 8 + (id & 7);
    ms = (id >> 3) & 7;
    ps = g & 7;
    z  = g >> 3;
}

// M[n,k] = s_k * cos(pi * k * (2n+1) / (2N)), bf16 (RNE-ish)
__global__ __launch_bounds__(256) void build_idct_matrix_bf16(short* __restrict__ M) {
    int idx = blockIdx.x * 256 + threadIdx.x;
    int n = idx >> 9;
    int k = idx & 511;
    int j = (k * (2 * n + 1)) & (4 * N512 - 1);
    float theta = (float)j * (3.14159265358979323846f / (2.0f * (float)N512));
    float s = (k == 0) ? 0.044194173824159216f : 0.0625f;
    M[idx] = f2bf(s * cosf(theta));
}

// ---------------------------------------------------------------------------
// Stage 1, per-wave autonomous: Tt[z][n][h] = sum_k M[n,k] * X[z][h,k]
// One 64-thread block = one wave = one 64x64 output tile. Private 16 KiB LDS.
// NO barriers: A via per-wave global_load_lds DMA; B(X fp32) via coalesced
// float4 reg loads -> cvt bf16 -> swizzled ds_write. Only per-wave vmcnt(0)
// + compiler lgkm waits. 10 independent wave-streams/CU hide all latency.
// ---------------------------------------------------------------------------
__global__ __launch_bounds__(64) void gemm_s1(const short* __restrict__ A,
                                              const float* __restrict__ Xg,
                                              short* __restrict__ Tg) {
    __shared__ __align__(16) short ldsA[8 * 512];   // 64x64 bf16, XOR-swizzled
    __shared__ __align__(16) short ldsB[8 * 512];

    const int l = threadIdx.x;       // 0..63
    const int q = (l >> 4) & 3;
    const int r = l & 15;

    int ms, ps, z;
    decode_wave(blockIdx.x, ms, ps, z);
    const int m0 = ms * 64;          // rows of M (output rows n of Tt)
    const int n0 = ps * 64;          // rows of X (output cols h of Tt)

    const float* Xs = Xg + ((long)z << 18);
    short* Tt = Tg + ((long)z << 18);

    // A DMA mapping: instr i covers tile rows i*8..i*8+7
    const int rsub = l >> 3;                 // row within 8-row chunk
    const int glog = (l & 7) ^ rsub;         // swizzled 16B-granule to fetch

    // B reg-load mapping: v[e] = float4 of row e*4+(l>>4), f4-index r
    const int brow = l >> 4;                 // 0..3

    floatx4 acc[4][4] = {};
    float4 v[16];

    for (int kt = 0; kt < 8; ++kt) {
        const int k0 = kt * 64;
        // A -> LDS via DMA (8 x 1KiB)
#pragma unroll
        for (int i = 0; i < 8; ++i)
            gload_lds16(A + (((long)(m0 + i * 8 + rsub)) << 9) + k0 + glog * 8,
                        ldsA + i * 512);
        // B: 16 coalesced float4 loads (full 64x64 fp32 sub-tile)
#pragma unroll
        for (int e = 0; e < 16; ++e) {
            const int rt = e * 4 + brow;
            v[e] = *(const float4*)(Xs + (((long)(n0 + rt)) << 9) + k0 + r * 4);
        }
        VMCNT0;   // per-wave: A landed in LDS, v[] ready. Other waves run on.
        // cvt + swizzled ds_write (row rt, granule (r>>1)^(rt&7), half r&1)
#pragma unroll
        for (int e = 0; e < 16; ++e) {
            const int rt = e * 4 + brow;
            short4 o;
            o.x = f2bf_fast(v[e].x);
            o.y = f2bf_fast(v[e].y);
            o.z = f2bf_fast(v[e].z);
            o.w = f2bf_fast(v[e].w);
            *(short4*)(ldsB + rt * 64 + (((r >> 1) ^ (rt & 7)) * 8) + (r & 1) * 4) = o;
        }
        // fragments + MFMA (compiler inserts lgkm waits for ds deps)
#pragma unroll
        for (int kk = 0; kk < 2; ++kk) {
            const int c = kk * 4 + q;
            const int goff = ((c ^ (r & 7)) * 8);
            short8 af[4], bfr[4];
#pragma unroll
            for (int i = 0; i < 4; ++i) {
                af[i]  = *(const short8*)(ldsA + (i * 16 + r) * 64 + goff);
                bfr[i] = *(const short8*)(ldsB + (i * 16 + r) * 64 + goff);
            }
#pragma unroll
            for (int i = 0; i < 4; ++i)
#pragma unroll
                for (int j = 0; j < 4; ++j)
                    acc[i][j] = __builtin_amdgcn_mfma_f32_16x16x32_bf16(
                        af[i], bfr[j], acc[i][j], 0, 0, 0);
        }
    }

    // epilogue: D row = q*4+rg, col = r; direct bf16 stores (L2 merges lines)
#pragma unroll
    for (int i = 0; i < 4; ++i) {
        const int mrow = m0 + i * 16 + q * 4;
#pragma unroll
        for (int j = 0; j < 4; ++j) {
            const int ncol = n0 + j * 16 + r;
#pragma unroll
            for (int rg = 0; rg < 4; ++rg)
                Tt[(long)(mrow + rg) * N512 + ncol] = f2bf(acc[i][j][rg]);
        }
    }
}

// ---------------------------------------------------------------------------
// Stage 2, per-wave autonomous: Out[z][m][n] = sum_h M[m,h] * Tt[z][n,h]
// Both operands bf16 via per-wave DMA. No barriers.
// ---------------------------------------------------------------------------
__global__ __launch_bounds__(64) void gemm_s2(const short* __restrict__ A,
                                              const short* __restrict__ Bg,
                                              float* __restrict__ Cg) {
    __shared__ __align__(16) short ldsA[8 * 512];
    __shared__ __align__(16) short ldsB[8 * 512];

    const int l = threadIdx.x;
    const int q = (l >> 4) & 3;
    const int r = l & 15;

    int ms, ps, z;
    decode_wave(blockIdx.x, ms, ps, z);
    const int m0 = ms * 64;          // rows of M (output rows m)
    const int n0 = ps * 64;          // rows of Tt (output cols n)

    const short* Bs = Bg + ((long)z << 18);
    float* C = Cg + ((long)z << 18);

    const int rsub = l >> 3;
    const int glog = (l & 7) ^ rsub;

    floatx4 acc[4][4] = {};

    for (int kt = 0; kt < 8; ++kt) {
        const int k0 = kt * 64;
#pragma unroll
        for (int i = 0; i < 8; ++i) {
            gload_lds16(A + (((long)(m0 + i * 8 + rsub)) << 9) + k0 + glog * 8,
                        ldsA + i * 512);
            gload_lds16(Bs + (((long)(n0 + i * 8 + rsub)) << 9) + k0 + glog * 8,
                        ldsB + i * 512);
        }
        VMCNT0;   // per-wave drain; other waves keep executing
#pragma unroll
        for (int kk = 0; kk < 2; ++kk) {
            const int c = kk * 4 + q;
            const int goff = ((c ^ (r & 7)) * 8);
            short8 af[4], bfr[4];
#pragma unroll
            for (int i = 0; i < 4; ++i) {
                af[i]  = *(const short8*)(ldsA + (i * 16 + r) * 64 + goff);
                bfr[i] = *(const short8*)(ldsB + (i * 16 + r) * 64 + goff);
            }
#pragma unroll
            for (int i = 0; i < 4; ++i)
#pragma unroll
                for (int j = 0; j < 4; ++j)
                    acc[i][j] = __builtin_amdgcn_mfma_f32_16x16x32_bf16(
                        af[i], bfr[j], acc[i][j], 0, 0, 0);
        }
    }

#pragma unroll
    for (int i = 0; i < 4; ++i) {
        const int mrow = m0 + i * 16 + q * 4;
#pragma unroll
        for (int j = 0; j < 4; ++j) {
            const int ncol = n0 + j * 16 + r;
#pragma unroll
            for (int rg = 0; rg < 4; ++rg)
                C[(long)(mrow + rg) * N512 + ncol] = acc[i][j][rg];
        }
    }
}

extern "C" void kernel_launch(void* const* d_in, const int* in_sizes, int n_in,
                              void* d_out, int out_size, void* d_ws, size_t ws_size,
                              hipStream_t stream) {
    const float* X = (const float*)d_in[0];
    float* out = (float*)d_out;

    const long plane = (long)N512 * N512;          // 262144
    const int slices = in_sizes[0] / (int)plane;   // 96

    short* Mb = (short*)d_ws;                      // 512 KB
    short* Tt = Mb + plane;                        // chunk * plane bf16

    long avail = (long)ws_size - plane * 2;        // bytes after M
    int chunk = (int)(avail / (plane * 2));        // bf16 plane per slice
    if (chunk > slices) chunk = slices;
    if (chunk < 1) chunk = 1;

    build_idct_matrix_bf16<<<dim3((int)(plane / 256)), dim3(256), 0, stream>>>(Mb);

    for (int s0 = 0; s0 < slices; s0 += chunk) {
        int c = (s0 + chunk <= slices) ? chunk : (slices - s0);
        // stage 1 (reads fp32 X directly): Tt[z][n][h] = sum_k M[n,k]*X[z][h,k]
        gemm_s1<<<dim3(64 * c), dim3(64), 0, stream>>>(
            Mb, X + (long)s0 * plane, Tt);
        // stage 2: Out[z][m][n] = sum_h M[m,h]*Tt[z][n,h]
        gemm_s2<<<dim3(64 * c), dim3(64), 0, stream>>>(
            Mb, Tt, out + (long)s0 * plane);
    }
}

// Round 4
// 246.308 us; speedup vs baseline: 1.0519x; 1.0519x over previous
//
#include <hip/hip_runtime.h>
#include <math.h>
#include <stdint.h>

#define N512 512

typedef __attribute__((ext_vector_type(8))) short short8;
typedef __attribute__((ext_vector_type(4))) float floatx4;

#define VMCNT0  asm volatile("s_waitcnt vmcnt(0)" ::: "memory")
#define LGKM0   asm volatile("s_waitcnt lgkmcnt(0)" ::: "memory")
#define BARRIER __builtin_amdgcn_s_barrier()

__device__ __forceinline__ short f2bf(float f) {
    uint32_t u = __float_as_uint(f);
    uint32_t r = u + 0x7fffu + ((u >> 16) & 1u);
    return (short)(r >> 16);
}

// cheap round-half-up (2 VALU): fine vs 0.109 threshold
__device__ __forceinline__ short f2bf_fast(float f) {
    return (short)((__float_as_uint(f) + 0x8000u) >> 16);
}

__device__ __forceinline__ void gload_lds16(const void* g, void* l) {
    __builtin_amdgcn_global_load_lds(
        (const __attribute__((address_space(1))) void*)g,
        (__attribute__((address_space(3))) void*)l,
        16, 0, 0);
}

// M[n,k] = s_k * cos(pi * k * (2n+1) / (2N)), bf16 (RNE-ish)
__global__ __launch_bounds__(256) void build_idct_matrix_bf16(short* __restrict__ M) {
    int idx = blockIdx.x * 256 + threadIdx.x;
    int n = idx >> 9;
    int k = idx & 511;
    int j = (k * (2 * n + 1)) & (4 * N512 - 1);
    float theta = (float)j * (3.14159265358979323846f / (2.0f * (float)N512));
    float s = (k == 0) ? 0.044194173824159216f : 0.0625f;
    M[idx] = f2bf(s * cosf(theta));
}

// One 16-MFMA phase: read A-frags for m-frag rows MF,MF+1, MFMA vs hoisted bfr.
// acc indices are macro-constants (rule #20: no runtime-indexed ext_vectors).
#define QUAD(MF)                                                                \
    do {                                                                        \
        short8 a00 = *(const short8*)(bufcA + (wm0 + (MF)*16 + r)*64 + gq0);    \
        short8 a01 = *(const short8*)(bufcA + (wm0 + (MF)*16 + r)*64 + gq1);    \
        short8 a10 = *(const short8*)(bufcA + (wm0 + (MF)*16 + 16 + r)*64 + gq0);\
        short8 a11 = *(const short8*)(bufcA + (wm0 + (MF)*16 + 16 + r)*64 + gq1);\
        __builtin_amdgcn_s_setprio(1);                                          \
        _Pragma("unroll")                                                       \
        for (int nf = 0; nf < 4; ++nf) {                                        \
            acc[(MF)][nf]     = __builtin_amdgcn_mfma_f32_16x16x32_bf16(        \
                a00, bfr[nf][0], acc[(MF)][nf], 0, 0, 0);                       \
            acc[(MF)][nf]     = __builtin_amdgcn_mfma_f32_16x16x32_bf16(        \
                a01, bfr[nf][1], acc[(MF)][nf], 0, 0, 0);                       \
            acc[(MF) + 1][nf] = __builtin_amdgcn_mfma_f32_16x16x32_bf16(        \
                a10, bfr[nf][0], acc[(MF) + 1][nf], 0, 0, 0);                   \
            acc[(MF) + 1][nf] = __builtin_amdgcn_mfma_f32_16x16x32_bf16(        \
                a11, bfr[nf][1], acc[(MF) + 1][nf], 0, 0, 0);                   \
        }                                                                       \
        __builtin_amdgcn_s_setprio(0);                                          \
    } while (0)

// ---------------------------------------------------------------------------
// Stage 1, 256x256 multi-phase: Tt[z][n][h] = sum_k M[n,k] * X[z][h,k]
// 8 waves (2m x 4n), per-wave 128x64 out, BK=64, LDS 2x(32KB A + 32KB B).
// Per K-tile: 4 phases x 16 MFMA with per-phase s_barrier + setprio (T3/T5).
// Tile t+1 staged at P0 (A: global_load_lds DMA; X: fp32 reg loads), waited
// at P3 (3-phase distance, loads in flight across barriers = T4/T14), then
// cvt->bf16 + swizzled ds_write.
// ---------------------------------------------------------------------------
__global__ __launch_bounds__(512, 2) void gemm_s1(const short* __restrict__ A,
                                                  const float* __restrict__ Xg,
                                                  short* __restrict__ Tg) {
    __shared__ __align__(16) short lds[2 * 32768];   // 128 KB: dbuf x (A|B)

    const int t = threadIdx.x;
    const int wv = t >> 6;           // wave 0..7
    const int l = t & 63;
    const int q = (l >> 4) & 3;
    const int r = l & 15;

    const int id = blockIdx.x;
    const int bn0 = (id & 1) * 256;          // X rows (h) / out cols
    const int bm0 = ((id >> 1) & 1) * 256;   // M rows (n) / out rows
    const int z = id >> 2;

    const int wm0 = (wv >> 2) * 128;         // 2 wave-rows
    const int wn0 = (wv & 3) * 64;           // 4 wave-cols

    const float* Xs = Xg + ((long)z << 18);
    short* Tt = Tg + ((long)z << 18);

    // A-DMA mapping (verified): chunk = 8 rows; lane covers row l>>3,
    // pre-swizzled granule (l&7)^(l>>3) on the GLOBAL address.
    const int rsub = l >> 3;
    const int glog = (l & 7) ^ rsub;

    // X staging: thread t covers rows rt = p*32 + (t>>4), float4 col t&15.
    const int trow = t >> 4;                 // 0..31
    const int tcol = t & 15;
    const int bg = tcol >> 1;
    const int bh = tcol & 1;

    const int gq0 = ((q ^ (r & 7)) * 8);
    const int gq1 = (((4 + q) ^ (r & 7)) * 8);

    floatx4 acc[8][4] = {};
    float4 v[8];

    // ---- prologue: fully stage K-tile 0 ----
#pragma unroll
    for (int i = 0; i < 4; ++i) {
        const int ch = wv * 4 + i;
        gload_lds16(A + (((long)(bm0 + ch * 8 + rsub)) << 9) + glog * 8,
                    lds + ch * 512);
    }
#pragma unroll
    for (int p = 0; p < 8; ++p) {
        const int rt = p * 32 + trow;
        v[p] = *(const float4*)(Xs + (((long)(bn0 + rt)) << 9) + tcol * 4);
    }
    VMCNT0;
#pragma unroll
    for (int p = 0; p < 8; ++p) {
        const int rt = p * 32 + trow;
        short4 o;
        o.x = f2bf_fast(v[p].x);
        o.y = f2bf_fast(v[p].y);
        o.z = f2bf_fast(v[p].z);
        o.w = f2bf_fast(v[p].w);
        *(short4*)(lds + 16384 + rt * 64 + ((bg ^ (rt & 7)) * 8) + bh * 4) = o;
    }
    LGKM0;
    BARRIER;

    for (int kt = 0; kt < 8; ++kt) {
        short* bufcA = lds + (kt & 1) * 32768;
        short* bufcB = bufcA + 16384;
        short* bufnA = lds + ((kt + 1) & 1) * 32768;
        short* bufnB = bufnA + 16384;

        // ---- P0: issue next-tile staging, hoist B-frags, 16 MFMA ----
        if (kt < 7) {
            const int k0n = (kt + 1) * 64;
#pragma unroll
            for (int i = 0; i < 4; ++i) {
                const int ch = wv * 4 + i;
                gload_lds16(A + (((long)(bm0 + ch * 8 + rsub)) << 9) + k0n + glog * 8,
                            bufnA + ch * 512);
            }
#pragma unroll
            for (int p = 0; p < 8; ++p) {
                const int rt = p * 32 + trow;
                v[p] = *(const float4*)(Xs + (((long)(bn0 + rt)) << 9) + k0n + tcol * 4);
            }
        }
        short8 bfr[4][2];
#pragma unroll
        for (int nf = 0; nf < 4; ++nf) {
            bfr[nf][0] = *(const short8*)(bufcB + (wn0 + nf * 16 + r) * 64 + gq0);
            bfr[nf][1] = *(const short8*)(bufcB + (wn0 + nf * 16 + r) * 64 + gq1);
        }
        QUAD(0);
        BARRIER;
        // ---- P1 ----
        QUAD(2);
        BARRIER;
        // ---- P2 ----
        QUAD(4);
        BARRIER;
        // ---- P3: last quad, then land next tile's B into LDS ----
        QUAD(6);
        if (kt < 7) {
            VMCNT0;   // A(t+1) DMA + v regs done; issued 3 phases ago
#pragma unroll
            for (int p = 0; p < 8; ++p) {
                const int rt = p * 32 + trow;
                short4 o;
                o.x = f2bf_fast(v[p].x);
                o.y = f2bf_fast(v[p].y);
                o.z = f2bf_fast(v[p].z);
                o.w = f2bf_fast(v[p].w);
                *(short4*)(bufnB + rt * 64 + ((bg ^ (rt & 7)) * 8) + bh * 4) = o;
            }
        }
        LGKM0;        // ds_writes retired before the iteration barrier
        BARRIER;
    }

    // epilogue: D row = q*4+rg (m-side), col = r (n-side); bf16 out
#pragma unroll
    for (int mf = 0; mf < 8; ++mf) {
        const int mrow = bm0 + wm0 + mf * 16 + q * 4;
#pragma unroll
        for (int nf = 0; nf < 4; ++nf) {
            const int ncol = bn0 + wn0 + nf * 16 + r;
#pragma unroll
            for (int rg = 0; rg < 4; ++rg)
                Tt[(long)(mrow + rg) * N512 + ncol] = f2bf(acc[mf][nf][rg]);
        }
    }
}

// ---------------------------------------------------------------------------
// Stage 2, same multi-phase structure: Out[z][m][n] = sum_h M[m,h]*Tt[z][n,h]
// Both operands bf16 via global_load_lds DMA (8 instr/wave at P0).
// ---------------------------------------------------------------------------
__global__ __launch_bounds__(512, 2) void gemm_s2(const short* __restrict__ A,
                                                  const short* __restrict__ Bg,
                                                  float* __restrict__ Cg) {
    __shared__ __align__(16) short lds[2 * 32768];

    const int t = threadIdx.x;
    const int wv = t >> 6;
    const int l = t & 63;
    const int q = (l >> 4) & 3;
    const int r = l & 15;

    const int id = blockIdx.x;
    const int bn0 = (id & 1) * 256;
    const int bm0 = ((id >> 1) & 1) * 256;
    const int z = id >> 2;

    const int wm0 = (wv >> 2) * 128;
    const int wn0 = (wv & 3) * 64;

    const short* Bs = Bg + ((long)z << 18);
    float* C = Cg + ((long)z << 18);

    const int rsub = l >> 3;
    const int glog = (l & 7) ^ rsub;

    const int gq0 = ((q ^ (r & 7)) * 8);
    const int gq1 = (((4 + q) ^ (r & 7)) * 8);

    floatx4 acc[8][4] = {};

    // ---- prologue: stage K-tile 0 (8 DMA/wave) ----
#pragma unroll
    for (int i = 0; i < 4; ++i) {
        const int ch = wv * 4 + i;
        gload_lds16(A + (((long)(bm0 + ch * 8 + rsub)) << 9) + glog * 8,
                    lds + ch * 512);
        gload_lds16(Bs + (((long)(bn0 + ch * 8 + rsub)) << 9) + glog * 8,
                    lds + 16384 + ch * 512);
    }
    VMCNT0;
    BARRIER;

    for (int kt = 0; kt < 8; ++kt) {
        short* bufcA = lds + (kt & 1) * 32768;
        short* bufcB = bufcA + 16384;
        short* bufnA = lds + ((kt + 1) & 1) * 32768;
        short* bufnB = bufnA + 16384;

        if (kt < 7) {
            const int k0n = (kt + 1) * 64;
#pragma unroll
            for (int i = 0; i < 4; ++i) {
                const int ch = wv * 4 + i;
                gload_lds16(A + (((long)(bm0 + ch * 8 + rsub)) << 9) + k0n + glog * 8,
                            bufnA + ch * 512);
                gload_lds16(Bs + (((long)(bn0 + ch * 8 + rsub)) << 9) + k0n + glog * 8,
                            bufnB + ch * 512);
            }
        }
        short8 bfr[4][2];
#pragma unroll
        for (int nf = 0; nf < 4; ++nf) {
            bfr[nf][0] = *(const short8*)(bufcB + (wn0 + nf * 16 + r) * 64 + gq0);
            bfr[nf][1] = *(const short8*)(bufcB + (wn0 + nf * 16 + r) * 64 + gq1);
        }
        QUAD(0);
        BARRIER;
        QUAD(2);
        BARRIER;
        QUAD(4);
        BARRIER;
        QUAD(6);
        if (kt < 7) VMCNT0;   // next tile's 8 DMAs done (3-phase distance)
        BARRIER;
    }

#pragma unroll
    for (int mf = 0; mf < 8; ++mf) {
        const int mrow = bm0 + wm0 + mf * 16 + q * 4;
#pragma unroll
        for (int nf = 0; nf < 4; ++nf) {
            const int ncol = bn0 + wn0 + nf * 16 + r;
#pragma unroll
            for (int rg = 0; rg < 4; ++rg)
                C[(long)(mrow + rg) * N512 + ncol] = acc[mf][nf][rg];
        }
    }
}

extern "C" void kernel_launch(void* const* d_in, const int* in_sizes, int n_in,
                              void* d_out, int out_size, void* d_ws, size_t ws_size,
                              hipStream_t stream) {
    const float* X = (const float*)d_in[0];
    float* out = (float*)d_out;

    const long plane = (long)N512 * N512;          // 262144
    const int slices = in_sizes[0] / (int)plane;   // 96

    short* Mb = (short*)d_ws;                      // 512 KB
    short* Tt = Mb + plane;                        // chunk * plane bf16

    long avail = (long)ws_size - plane * 2;        // bytes after M
    int chunk = (int)(avail / (plane * 2));        // bf16 plane per slice
    if (chunk > slices) chunk = slices;
    if (chunk < 1) chunk = 1;

    build_idct_matrix_bf16<<<dim3((int)(plane / 256)), dim3(256), 0, stream>>>(Mb);

    for (int s0 = 0; s0 < slices; s0 += chunk) {
        int c = (s0 + chunk <= slices) ? chunk : (slices - s0);
        // stage 1 (reads fp32 X directly): Tt[z][n][h] = sum_k M[n,k]*X[z][h,k]
        gemm_s1<<<dim3(4 * c), dim3(512), 0, stream>>>(
            Mb, X + (long)s0 * plane, Tt);
        // stage 2: Out[z][m][n] = sum_h M[m,h]*Tt[z][n,h]
        gemm_s2<<<dim3(4 * c), dim3(512), 0, stream>>>(
            Mb, Tt, out + (long)s0 * plane);
    }
}